// Round 7
// baseline (666.567 us; speedup 1.0000x reference)
//
#include <hip/hip_runtime.h>
#include <hip/hip_fp16.h>
#include <math.h>

#define NNODES 40000
#define NEDGES 640000
#define NGRAPH 64
#define CAP 96                 // slots per dst bucket (max random-degree ~45)
constexpr float LN_EPS = 1e-5f;

// R1 LESSON (measured): multi-line divergent VMEM collapses throughput 4x.
//   SGPR-base + contiguous lane offset, ONE row per VMEM instruction, mandatory.
// R2 LESSON (measured): 2 nodes/wave interleaved = best aggr point.
// R3 LESSON (measured): 4 chains/wave REGRESSED (occupancy + imbalance).
// R4 LESSON (measured): fp16 MFMA GEMM works; 245.6us.
// R5 LESSON (measured): per-block W2 staging x5000 blocks = L2 thrash (+38MB HBM).
// R6 LESSON (measured): LDS-staged gemm A-tiles + fp16 intermediate -> 242us (best).
//   Aggr cross-session noise band 53-73us; scattered-request service wall
//   (~1 row-load/60cy/CU, insensitive to bytes/depth) is the aggr floor.
// R7: epilogue shuffle ILP (paired A/B LN reductions); aggr2 pool atomics
//   flattened via block-LDS reduction (625 adds/address -> ~1/block); head fused
//   into aggr2's last block (one fewer dispatch).

typedef _Float16 v8h __attribute__((ext_vector_type(8)));
typedef float    v4f __attribute__((ext_vector_type(4)));

// ================= butterfly wave reductions =================
__device__ __forceinline__ float bf_sum(float v) {
    #pragma unroll
    for (int o = 32; o > 0; o >>= 1) v += __shfl_xor(v, o);
    return v;
}
__device__ __forceinline__ void bf_sum2(float& a, float& b) {
    #pragma unroll
    for (int o = 32; o > 0; o >>= 1) {   // interleaved: 2 chains, ILP overlapped
        a += __shfl_xor(a, o);
        b += __shfl_xor(b, o);
    }
}

// ====== bin_edges + W1/W2 MFMA B-frag build + sums/ctr zero (cnt via memset) =======
// B-frag layout for v_mfma_f32_16x16x32_f16: lane l = g*16+lc holds B[k][n] with
// n = lc, k = ks*32 + g*8 + j (j=0..7). Same (g,j)->k map as the A frags below.
__global__ void bin_prep(const int* __restrict__ ei, int E,
                         int* __restrict__ cnt, unsigned short* __restrict__ ssrc,
                         const float* __restrict__ W1, const float* __restrict__ W2,
                         _Float16* __restrict__ Bf1, _Float16* __restrict__ Bf2,
                         float* __restrict__ sums, int* __restrict__ ctr) {
    const int t = blockIdx.x * blockDim.x + threadIdx.x;
    if (t == 0) *ctr = 0;
    if (t < 128 * 128) {
        const int o = t >> 7, k = t & 127;             // W1[o][k]
        const int nt = o >> 4, lc = o & 15;
        const int ks = k >> 5, g = (k >> 3) & 3, j = k & 7;
        Bf1[(size_t)(((nt * 4 + ks) * 64 + g * 16 + lc) * 8 + j)] = (_Float16)W1[t];
    }
    if (t < 64 * 128) {
        const int o = t >> 7, k = t & 127;             // W2[o][k]
        const int nt = o >> 4, lc = o & 15;
        const int ks = k >> 5, g = (k >> 3) & 3, j = k & 7;
        Bf2[(size_t)(((nt * 4 + ks) * 64 + g * 16 + lc) * 8 + j)] = (_Float16)W2[t];
    }
    if (t < NGRAPH * 64) sums[t] = 0.f;
    if (t < E) {
        const int s = ei[t], d = ei[E + t];
        const int pos = atomicAdd(cnt + d, 1);
        if (pos < CAP) ssrc[d * CAP + pos] = (unsigned short)s;
    }
}

// ================= GEMM + scores via MFMA; A-tile staged through LDS ===============
template<int DOUT, bool F16IN>
__global__ __launch_bounds__(256) void gemm_scores_mfma(
        const void* __restrict__ Xin, const _Float16* __restrict__ Bfrag,
        const float* __restrict__ asrc, const float* __restrict__ adst,
        __half* __restrict__ H, float* __restrict__ S, float* __restrict__ Dv) {
    constexpr int NT = DOUT / 16;
    __shared__ _Float16 xs[64][136];
    const int tid = threadIdx.x;
    const int base = blockIdx.x * 64;

    if (F16IN) {
        const _Float16* Xh = (const _Float16*)Xin;
        for (int c = tid; c < 64 * 16; c += 256) {          // 16B chunks, coalesced
            const int row = c >> 4, c8 = c & 15;
            *(float4*)&xs[row][c8 * 8] =
                *(const float4*)(Xh + (size_t)(base + row) * 128 + c8 * 8);
        }
    } else {
        const float* Xf = (const float*)Xin;
        for (int c = tid; c < 64 * 32; c += 256) {          // float4 chunks, coalesced
            const int row = c >> 5, c4 = c & 31;
            const float4 v = *(const float4*)(Xf + (size_t)(base + row) * 128 + c4 * 4);
            _Float16 h4[4] = {(_Float16)v.x, (_Float16)v.y, (_Float16)v.z, (_Float16)v.w};
            *(uint2*)&xs[row][c4 * 4] = *(const uint2*)h4;
        }
    }
    __syncthreads();

    const int lane = tid & 63;
    const int wv   = tid >> 6;
    const int nb   = base + wv * 16;
    const int lc = lane & 15, g = lane >> 4;

    v8h a[4];
    #pragma unroll
    for (int ks = 0; ks < 4; ++ks)
        a[ks] = *(const v8h*)&xs[wv * 16 + lc][ks * 32 + g * 8];

    v4f acc[NT];
    #pragma unroll
    for (int nt = 0; nt < NT; ++nt) acc[nt] = (v4f){0.f, 0.f, 0.f, 0.f};

    #pragma unroll
    for (int ks = 0; ks < 4; ++ks) {
        #pragma unroll
        for (int nt = 0; nt < NT; ++nt) {
            const v8h bv = *(const v8h*)(Bfrag + (size_t)(((nt * 4 + ks) * 64 + lane) * 8));
            acc[nt] = __builtin_amdgcn_mfma_f32_16x16x32_f16(a[ks], bv, acc[nt], 0, 0, 0);
        }
    }

    float sp[4] = {0.f, 0.f, 0.f, 0.f}, dp[4] = {0.f, 0.f, 0.f, 0.f};
    #pragma unroll
    for (int nt = 0; nt < NT; ++nt) {
        const float as_ = asrc[nt * 16 + lc];
        const float ad_ = adst[nt * 16 + lc];
        #pragma unroll
        for (int r = 0; r < 4; ++r) {
            const float hv = acc[nt][r];
            H[(size_t)(nb + g * 4 + r) * DOUT + nt * 16 + lc] = __float2half_rn(hv);
            sp[r] += hv * as_;
            dp[r] += hv * ad_;
        }
    }
    #pragma unroll
    for (int o = 8; o > 0; o >>= 1) {
        #pragma unroll
        for (int r = 0; r < 4; ++r) {
            sp[r] += __shfl_xor(sp[r], o);
            dp[r] += __shfl_xor(dp[r], o);
        }
    }
    #pragma unroll
    for (int r = 0; r < 4; ++r) {
        if (lc == r) {
            S[nb + g * 4 + r]  = sp[r];
            Dv[nb + g * 4 + r] = dp[r];
        }
    }
}

// ================= generic single-node aggregation (rare big-deg path) ==============
template<int D>
__device__ __forceinline__ void aggr_one_generic(
        const int node, const int deg, const int lane,
        const unsigned short* __restrict__ ssrc, const float* __restrict__ S,
        const float dsc, const __half* __restrict__ H,
        float& acc0, float& acc1, float& z) {
    constexpr int VPL = D / 64;
    float zz = 0.f;
    const int r0 = node * CAP;
    for (int bse = 0; bse < deg; bse += 64) {
        const int n = min(64, deg - bse);
        int s = 0; float a = 0.f;
        if (lane < n) {
            s = ssrc[r0 + bse + lane];
            float t = S[s] + dsc;
            t = t > 0.f ? t : 0.2f * t;
            a = __expf(t);
        }
        zz += bf_sum(a);
        const int abits = __float_as_int(a);
        for (int j = 0; j < n; ++j) {
            const int sj = __builtin_amdgcn_readlane(s, j);
            const float aj = __int_as_float(__builtin_amdgcn_readlane(abits, j));
            const __half* hp = H + (size_t)sj * D;
            if (VPL == 1) {
                acc0 += aj * __half2float(hp[lane]);
            } else {
                const float2 f = __half22float2(*(const __half2*)(hp + 2 * lane));
                acc0 += aj * f.x; acc1 += aj * f.y;
            }
        }
    }
    z = zz;
}

// ====== LN for a node PAIR with interleaved reductions (2 serial chains, not 4) =====
template<int D>
__device__ __forceinline__ void ln_pair(
        float accA0, float accA1, float zA, const float aselfA, const float2 sfA,
        float accB0, float accB1, float zB, const float aselfB, const float2 sfB,
        const int lane,
        const float* __restrict__ b, const float* __restrict__ gam,
        const float* __restrict__ bet, float vA[2], float vB[2]) {
    constexpr int VPL = D / 64;
    accA0 += aselfA * sfA.x; accB0 += aselfB * sfB.x;
    if (VPL == 2) { accA1 += aselfA * sfA.y; accB1 += aselfB * sfB.y; }
    zA += aselfA; zB += aselfB;
    const float ziA = 1.0f / zA, ziB = 1.0f / zB;
    const int ch0 = VPL * lane;
    float lsA, lsB;
    vA[0] = fmaxf(accA0 * ziA + b[ch0], 0.f);
    vB[0] = fmaxf(accB0 * ziB + b[ch0], 0.f);
    lsA = vA[0]; lsB = vB[0];
    if (VPL == 2) {
        vA[1] = fmaxf(accA1 * ziA + b[ch0 + 1], 0.f);
        vB[1] = fmaxf(accB1 * ziB + b[ch0 + 1], 0.f);
        lsA += vA[1]; lsB += vB[1];
    }
    bf_sum2(lsA, lsB);
    const float muA = lsA / D, muB = lsB / D;
    float qA, qB;
    vA[0] -= muA; qA = vA[0] * vA[0];
    vB[0] -= muB; qB = vB[0] * vB[0];
    if (VPL == 2) {
        vA[1] -= muA; qA += vA[1] * vA[1];
        vB[1] -= muB; qB += vB[1] * vB[1];
    }
    bf_sum2(qA, qB);
    const float rsA = rsqrtf(qA / D + LN_EPS), rsB = rsqrtf(qB / D + LN_EPS);
    const float g0 = gam[ch0], e0 = bet[ch0];
    vA[0] = g0 * vA[0] * rsA + e0;
    vB[0] = g0 * vB[0] * rsB + e0;
    if (VPL == 2) {
        const float g1 = gam[ch0 + 1], e1 = bet[ch0 + 1];
        vA[1] = g1 * vA[1] * rsA + e1;
        vB[1] = g1 * vB[1] * rsB + e1;
    }
}

// ================= fused GAT: TWO nodes per wave (R2 form) ==========================
// POOL=1 additionally: block-LDS pool reduction + last-block fused head.
template<int D, int POOL>
__global__ __launch_bounds__(256) void gat_aggr(
        const int* __restrict__ cnt, const unsigned short* __restrict__ ssrc,
        const float* __restrict__ S, const float* __restrict__ Dv,
        const __half* __restrict__ H,
        const float* __restrict__ b, const float* __restrict__ gam,
        const float* __restrict__ bet,
        __half* __restrict__ outh, const int* __restrict__ batch,
        float* __restrict__ sums, int* __restrict__ ctr,
        const float* __restrict__ Wl, const float* __restrict__ bl,
        const float* __restrict__ Wc, const float* __restrict__ bc,
        float* __restrict__ out) {
    constexpr int VPL = D / 64;
    __shared__ float psum[64];
    __shared__ int pbg;
    __shared__ int lastFlag;
    if (POOL) {
        if (threadIdx.x == 0) pbg = batch[blockIdx.x * 8];
        if (threadIdx.x < 64) psum[threadIdx.x] = 0.f;
        __syncthreads();
    }

    const int lane = threadIdx.x & 63;
    const int wv   = threadIdx.x >> 6;
    const int nodeA = blockIdx.x * 8 + wv * 2;      // 2 nodes per wave
    const int nodeB = nodeA + 1;

    const int degA = min(__builtin_amdgcn_readfirstlane(cnt[nodeA]), CAP);
    const int degB = min(__builtin_amdgcn_readfirstlane(cnt[nodeB]), CAP);
    const float dscA = Dv[nodeA], dscB = Dv[nodeB];

    float tsA = S[nodeA] + dscA; tsA = tsA > 0.f ? tsA : 0.2f * tsA;
    float tsB = S[nodeB] + dscB; tsB = tsB > 0.f ? tsB : 0.2f * tsB;
    const float aselfA = __expf(tsA);
    const float aselfB = __expf(tsB);

    float2 selfFA, selfFB;
    if (VPL == 1) {
        selfFA = make_float2(__half2float(H[(size_t)nodeA * D + lane]), 0.f);
        selfFB = make_float2(__half2float(H[(size_t)nodeB * D + lane]), 0.f);
    } else {
        selfFA = __half22float2(*(const __half2*)(H + (size_t)nodeA * D + 2 * lane));
        selfFB = __half22float2(*(const __half2*)(H + (size_t)nodeB * D + 2 * lane));
    }

    float accA0 = 0.f, accA1 = 0.f, accB0 = 0.f, accB1 = 0.f;
    float zA, zB;

    if (degA <= 64 && degB <= 64) {
        int sA = 0, sB = 0;
        if (lane < degA) sA = ssrc[nodeA * CAP + lane];
        if (lane < degB) sB = ssrc[nodeB * CAP + lane];
        float tA = S[sA] + dscA;                    // idle lanes read S[0]: harmless
        float tB = S[sB] + dscB;
        tA = tA > 0.f ? tA : 0.2f * tA;
        tB = tB > 0.f ? tB : 0.2f * tB;
        const float aA = (lane < degA) ? __expf(tA) : 0.f;
        const float aB = (lane < degB) ? __expf(tB) : 0.f;
        zA = aA; zB = aB;
        bf_sum2(zA, zB);
        const int abA = __float_as_int(aA), abB = __float_as_int(aB);

        const int nmA = (degA + 7) & ~7;
        const int nmB = (degB + 7) & ~7;
        const int nmax = max(nmA, nmB);
        for (int j = 0; j < nmax; j += 8) {
            const bool doA = j < nmA, doB = j < nmB;   // wave-uniform
            float afA[8], afB[8];
            __half2 hvA[8], hvB[8];
            __half hsA[8], hsB[8];
            if (doA) {
                #pragma unroll
                for (int u = 0; u < 8; ++u) {
                    const int sj = __builtin_amdgcn_readlane(sA, j + u);
                    afA[u] = __int_as_float(__builtin_amdgcn_readlane(abA, j + u));
                    const __half* hp = H + (size_t)sj * D;
                    if (VPL == 1) hsA[u] = hp[lane];
                    else          hvA[u] = *(const __half2*)(hp + 2 * lane);
                }
            }
            if (doB) {
                #pragma unroll
                for (int u = 0; u < 8; ++u) {
                    const int sj = __builtin_amdgcn_readlane(sB, j + u);
                    afB[u] = __int_as_float(__builtin_amdgcn_readlane(abB, j + u));
                    const __half* hp = H + (size_t)sj * D;
                    if (VPL == 1) hsB[u] = hp[lane];
                    else          hvB[u] = *(const __half2*)(hp + 2 * lane);
                }
            }
            if (doA) {
                #pragma unroll
                for (int u = 0; u < 8; ++u) {
                    if (VPL == 1) {
                        accA0 += afA[u] * __half2float(hsA[u]);
                    } else {
                        accA0 += afA[u] * __half2float(__low2half(hvA[u]));
                        accA1 += afA[u] * __half2float(__high2half(hvA[u]));
                    }
                }
            }
            if (doB) {
                #pragma unroll
                for (int u = 0; u < 8; ++u) {
                    if (VPL == 1) {
                        accB0 += afB[u] * __half2float(hsB[u]);
                    } else {
                        accB0 += afB[u] * __half2float(__low2half(hvB[u]));
                        accB1 += afB[u] * __half2float(__high2half(hvB[u]));
                    }
                }
            }
        }
    } else {
        aggr_one_generic<D>(nodeA, degA, lane, ssrc, S, dscA, H, accA0, accA1, zA);
        aggr_one_generic<D>(nodeB, degB, lane, ssrc, S, dscB, H, accB0, accB1, zB);
    }

    float vA[2], vB[2];
    ln_pair<D>(accA0, accA1, zA, aselfA, selfFA,
               accB0, accB1, zB, aselfB, selfFB,
               lane, b, gam, bet, vA, vB);

    if (!POOL) {
        if (VPL == 2) {
            *(__half2*)(outh + (size_t)nodeA * D + 2 * lane) = __floats2half2_rn(vA[0], vA[1]);
            *(__half2*)(outh + (size_t)nodeB * D + 2 * lane) = __floats2half2_rn(vB[0], vB[1]);
        } else {
            outh[(size_t)nodeA * D + lane] = __float2half_rn(vA[0]);
            outh[(size_t)nodeB * D + lane] = __float2half_rn(vB[0]);
        }
    } else {
        // ---- block-level pool reduction (batch sorted -> blocks rarely straddle) ----
        const int bgA = batch[nodeA], bgB = batch[nodeB];
        const int pb = pbg;
        if (bgA == pb) atomicAdd(&psum[lane], vA[0]);
        else           atomicAdd(&sums[bgA * 64 + lane], vA[0]);
        if (bgB == pb) atomicAdd(&psum[lane], vB[0]);
        else           atomicAdd(&sums[bgB * 64 + lane], vB[0]);
        __syncthreads();
        if (threadIdx.x < 64) atomicAdd(&sums[pb * 64 + threadIdx.x], psum[threadIdx.x]);
        __threadfence();                             // sums visible before ctr bump
        __syncthreads();
        if (threadIdx.x == 0)
            lastFlag = (atomicAdd(ctr, 1) == (int)gridDim.x - 1);
        __syncthreads();

        // ---- last block: fused head (4 graphs/wave-pass x 16 passes) ----
        if (lastFlag) {
            for (int g0 = 0; g0 < NGRAPH; g0 += 4) {
                const int g = g0 + wv;
                int lo = 0, hi = NNODES;
                while (lo < hi) { int m = (lo + hi) >> 1; if (batch[m] < g) lo = m + 1; else hi = m; }
                int lo2 = lo, hi2 = NNODES;
                while (lo2 < hi2) { int m = (lo2 + hi2) >> 1; if (batch[m] < g + 1) lo2 = m + 1; else hi2 = m; }
                const float c = fmaxf((float)(lo2 - lo), 1.0f);
                // atomic read: guaranteed coherent view of other blocks' atomics
                const float pv = atomicAdd(&sums[g * 64 + lane], 0.f) / c;
                float t = bl[lane];
                for (int k = 0; k < 64; ++k)
                    t += Wl[lane * 64 + k] * __shfl(pv, k);
                const float r = bf_sum(Wc[lane] * t);
                if (lane == 0) out[g] = r + bc[0];
            }
        }
    }
}

extern "C" void kernel_launch(void* const* d_in, const int* in_sizes, int n_in,
                              void* d_out, int out_size, void* d_ws, size_t ws_size,
                              hipStream_t stream) {
    const int N = NNODES, E = NEDGES, G = NGRAPH;

    const float* x      = (const float*)d_in[0];
    const int*   ei     = (const int*)d_in[1];
    const int*   batch  = (const int*)d_in[2];
    const float* W1     = (const float*)d_in[3];
    const float* a1s    = (const float*)d_in[4];
    const float* a1d    = (const float*)d_in[5];
    const float* b1     = (const float*)d_in[6];
    const float* g1     = (const float*)d_in[7];
    const float* be1    = (const float*)d_in[8];
    const float* W2     = (const float*)d_in[9];
    const float* a2s    = (const float*)d_in[10];
    const float* a2d    = (const float*)d_in[11];
    const float* b2     = (const float*)d_in[12];
    const float* g2     = (const float*)d_in[13];
    const float* be2    = (const float*)d_in[14];
    const float* Wl     = (const float*)d_in[15];
    const float* bl     = (const float*)d_in[16];
    const float* Wc     = (const float*)d_in[17];
    const float* bc     = (const float*)d_in[18];

    // ---- workspace carve-up ----
    char* w = (char*)d_ws;
    __half* h1   = (__half*)w; w += (size_t)N * 128 * 2;   // fp16 H layer 1
    __half* v1h  = (__half*)w; w += (size_t)N * 128 * 2;   // fp16 LN'd layer-1 out
    __half* h2   = (__half*)w; w += (size_t)N * 64 * 2;    // fp16 H layer 2
    float* S1    = (float*)w; w += (size_t)N * 4;
    float* Dv1   = (float*)w; w += (size_t)N * 4;
    float* S2    = (float*)w; w += (size_t)N * 4;
    float* Dv2   = (float*)w; w += (size_t)N * 4;
    int* cnt     = (int*)w;   w += (size_t)N * 4;
    unsigned short* ssrc = (unsigned short*)w; w += (size_t)N * CAP * 2;
    _Float16* Bf1 = (_Float16*)w; w += (size_t)128 * 128 * 2;   // MFMA B-frags W1
    _Float16* Bf2 = (_Float16*)w; w += (size_t)64 * 128 * 2;    // MFMA B-frags W2
    float* sums  = (float*)w; w += (size_t)G * 64 * 4;
    int* ctr     = (int*)w;  w += 64;                           // done-counter

    const int TB = 256;

    // ---- zero cnt (capture-safe), then binning + W-frag prep in one kernel ----
    hipMemsetAsync(cnt, 0, (size_t)N * 4, stream);
    bin_prep<<<(E + TB - 1) / TB, TB, 0, stream>>>(ei, E, cnt, ssrc, W1, W2,
                                                   Bf1, Bf2, sums, ctr);

    // ---- layer 1 GEMM (128 -> 128), fp32 input staged via LDS ----
    gemm_scores_mfma<128, false><<<N / 64, 256, 0, stream>>>(x, Bf1, a1s, a1d,
                                                             h1, S1, Dv1);

    // ---- layer 1 aggregation + LN -> fp16 v1h ----
    gat_aggr<128, 0><<<N / 8, 256, 0, stream>>>(cnt, ssrc, S1, Dv1, h1, b1, g1, be1,
                                                v1h, nullptr, nullptr, nullptr,
                                                nullptr, nullptr, nullptr, nullptr,
                                                nullptr);

    // ---- layer 2 GEMM (128 -> 64), fp16 input staged via LDS ----
    gemm_scores_mfma<64, true><<<N / 64, 256, 0, stream>>>(v1h, Bf2, a2s, a2d,
                                                           h2, S2, Dv2);

    // ---- layer 2 aggregation + LN + block-pooled sums + fused head ----
    gat_aggr<64, 1><<<N / 8, 256, 0, stream>>>(cnt, ssrc, S2, Dv2, h2, b2, g2, be2,
                                               nullptr, batch, sums, ctr,
                                               Wl, bl, Wc, bc, (float*)d_out);
}

// Round 8
// 245.472 us; speedup vs baseline: 2.7154x; 2.7154x over previous
//
#include <hip/hip_runtime.h>
#include <hip/hip_fp16.h>
#include <math.h>

#define NNODES 40000
#define NEDGES 640000
#define NGRAPH 64
#define CAP 96                 // slots per dst bucket (max random-degree ~45)
constexpr float LN_EPS = 1e-5f;

// R1 LESSON (measured): multi-line divergent VMEM collapses throughput 4x.
//   SGPR-base + contiguous lane offset, ONE row per VMEM instruction, mandatory.
// R2 LESSON (measured): 2 nodes/wave interleaved = best aggr point.
// R3 LESSON (measured): 4 chains/wave REGRESSED (occupancy + imbalance).
// R4 LESSON (measured): fp16 MFMA GEMM works; 245.6us.
// R5 LESSON (measured): per-block W2 staging x5000 blocks = L2 thrash (+38MB HBM).
// R6 LESSON (measured): LDS-staged gemm A-tiles + fp16 intermediate -> 242us (BEST).
//   Aggr cross-session noise band 53-73us; scattered-request service wall
//   (~1 row-load/60cy/CU, insensitive to bytes/depth) is the aggr floor.
// R7 LESSON (measured): __threadfence() per block on XCD-noncoherent L2 = L2
//   writeback x5000 blocks -> aggr2 60->502us (VALUBusy 2.8%). NEVER fence /
//   grid-sync per block; a separate tiny dispatch is cheaper. Full revert to R6.

typedef _Float16 v8h __attribute__((ext_vector_type(8)));
typedef float    v4f __attribute__((ext_vector_type(4)));

// ================= butterfly wave reduction (all lanes get result) =================
__device__ __forceinline__ float bf_sum(float v) {
    #pragma unroll
    for (int o = 32; o > 0; o >>= 1) v += __shfl_xor(v, o);
    return v;
}

// ====== bin_edges + W1/W2 MFMA B-frag build + sums zero (cnt zeroed by memset) =====
// B-frag layout for v_mfma_f32_16x16x32_f16: lane l = g*16+lc holds B[k][n] with
// n = lc, k = ks*32 + g*8 + j (j=0..7). Same (g,j)->k map as the A frags below.
__global__ void bin_prep(const int* __restrict__ ei, int E,
                         int* __restrict__ cnt, unsigned short* __restrict__ ssrc,
                         const float* __restrict__ W1, const float* __restrict__ W2,
                         _Float16* __restrict__ Bf1, _Float16* __restrict__ Bf2,
                         float* __restrict__ sums) {
    const int t = blockIdx.x * blockDim.x + threadIdx.x;
    if (t < 128 * 128) {
        const int o = t >> 7, k = t & 127;             // W1[o][k]
        const int nt = o >> 4, lc = o & 15;
        const int ks = k >> 5, g = (k >> 3) & 3, j = k & 7;
        Bf1[(size_t)(((nt * 4 + ks) * 64 + g * 16 + lc) * 8 + j)] = (_Float16)W1[t];
    }
    if (t < 64 * 128) {
        const int o = t >> 7, k = t & 127;             // W2[o][k]
        const int nt = o >> 4, lc = o & 15;
        const int ks = k >> 5, g = (k >> 3) & 3, j = k & 7;
        Bf2[(size_t)(((nt * 4 + ks) * 64 + g * 16 + lc) * 8 + j)] = (_Float16)W2[t];
    }
    if (t < NGRAPH * 64) sums[t] = 0.f;
    if (t < E) {
        const int s = ei[t], d = ei[E + t];
        const int pos = atomicAdd(cnt + d, 1);
        if (pos < CAP) ssrc[d * CAP + pos] = (unsigned short)s;
    }
}

// ================= GEMM + scores via MFMA; A-tile staged through LDS ===============
// Block: 64 nodes, 4 waves; per wave one 16-node M-tile x DOUT, K=128 in 4 ksteps.
// Staging is fully coalesced; LDS row stride 136 halfs (272B, 16B-aligned) gives
// <=2-way bank aliasing (free) on the v8h fragment reads.
template<int DOUT, bool F16IN>
__global__ __launch_bounds__(256) void gemm_scores_mfma(
        const void* __restrict__ Xin, const _Float16* __restrict__ Bfrag,
        const float* __restrict__ asrc, const float* __restrict__ adst,
        __half* __restrict__ H, float* __restrict__ S, float* __restrict__ Dv) {
    constexpr int NT = DOUT / 16;
    __shared__ _Float16 xs[64][136];
    const int tid = threadIdx.x;
    const int base = blockIdx.x * 64;

    if (F16IN) {
        const _Float16* Xh = (const _Float16*)Xin;
        for (int c = tid; c < 64 * 16; c += 256) {          // 16B chunks, coalesced
            const int row = c >> 4, c8 = c & 15;
            *(float4*)&xs[row][c8 * 8] =
                *(const float4*)(Xh + (size_t)(base + row) * 128 + c8 * 8);
        }
    } else {
        const float* Xf = (const float*)Xin;
        for (int c = tid; c < 64 * 32; c += 256) {          // float4 chunks, coalesced
            const int row = c >> 5, c4 = c & 31;
            const float4 v = *(const float4*)(Xf + (size_t)(base + row) * 128 + c4 * 4);
            _Float16 h4[4] = {(_Float16)v.x, (_Float16)v.y, (_Float16)v.z, (_Float16)v.w};
            *(uint2*)&xs[row][c4 * 4] = *(const uint2*)h4;
        }
    }
    __syncthreads();

    const int lane = tid & 63;
    const int wv   = tid >> 6;
    const int nb   = base + wv * 16;
    const int lc = lane & 15, g = lane >> 4;

    v8h a[4];
    #pragma unroll
    for (int ks = 0; ks < 4; ++ks)
        a[ks] = *(const v8h*)&xs[wv * 16 + lc][ks * 32 + g * 8];

    v4f acc[NT];
    #pragma unroll
    for (int nt = 0; nt < NT; ++nt) acc[nt] = (v4f){0.f, 0.f, 0.f, 0.f};

    #pragma unroll
    for (int ks = 0; ks < 4; ++ks) {
        #pragma unroll
        for (int nt = 0; nt < NT; ++nt) {
            const v8h bv = *(const v8h*)(Bfrag + (size_t)(((nt * 4 + ks) * 64 + lane) * 8));
            acc[nt] = __builtin_amdgcn_mfma_f32_16x16x32_f16(a[ks], bv, acc[nt], 0, 0, 0);
        }
    }

    float sp[4] = {0.f, 0.f, 0.f, 0.f}, dp[4] = {0.f, 0.f, 0.f, 0.f};
    #pragma unroll
    for (int nt = 0; nt < NT; ++nt) {
        const float as_ = asrc[nt * 16 + lc];
        const float ad_ = adst[nt * 16 + lc];
        #pragma unroll
        for (int r = 0; r < 4; ++r) {
            const float hv = acc[nt][r];
            H[(size_t)(nb + g * 4 + r) * DOUT + nt * 16 + lc] = __float2half_rn(hv);
            sp[r] += hv * as_;
            dp[r] += hv * ad_;
        }
    }
    #pragma unroll
    for (int o = 8; o > 0; o >>= 1) {
        #pragma unroll
        for (int r = 0; r < 4; ++r) {
            sp[r] += __shfl_xor(sp[r], o);
            dp[r] += __shfl_xor(dp[r], o);
        }
    }
    #pragma unroll
    for (int r = 0; r < 4; ++r) {
        if (lc == r) {
            S[nb + g * 4 + r]  = sp[r];
            Dv[nb + g * 4 + r] = dp[r];
        }
    }
}

// ================= generic single-node aggregation (rare big-deg path) ==============
template<int D>
__device__ __forceinline__ void aggr_one_generic(
        const int node, const int deg, const int lane,
        const unsigned short* __restrict__ ssrc, const float* __restrict__ S,
        const float dsc, const __half* __restrict__ H,
        float& acc0, float& acc1, float& z) {
    constexpr int VPL = D / 64;
    float zz = 0.f;
    const int r0 = node * CAP;
    for (int bse = 0; bse < deg; bse += 64) {
        const int n = min(64, deg - bse);
        int s = 0; float a = 0.f;
        if (lane < n) {
            s = ssrc[r0 + bse + lane];
            float t = S[s] + dsc;
            t = t > 0.f ? t : 0.2f * t;
            a = __expf(t);
        }
        zz += bf_sum(a);
        const int abits = __float_as_int(a);
        for (int j = 0; j < n; ++j) {
            const int sj = __builtin_amdgcn_readlane(s, j);
            const float aj = __int_as_float(__builtin_amdgcn_readlane(abits, j));
            const __half* hp = H + (size_t)sj * D;
            if (VPL == 1) {
                acc0 += aj * __half2float(hp[lane]);
            } else {
                const float2 f = __half22float2(*(const __half2*)(hp + 2 * lane));
                acc0 += aj * f.x; acc1 += aj * f.y;
            }
        }
    }
    z = zz;
}

// ===== epilogue: self-loop + normalize + bias + ReLU + LN + store (fp16 or pool) ====
template<int D, int POOL>
__device__ __forceinline__ void finish_node(
        const int node, const int lane,
        float acc0, float acc1, float z, const float aself, const float2 selfF,
        const float* __restrict__ b, const float* __restrict__ gam,
        const float* __restrict__ bet,
        __half* __restrict__ outh, const int* __restrict__ batch,
        float* __restrict__ sums) {
    constexpr int VPL = D / 64;
    acc0 += aself * selfF.x;
    if (VPL == 2) acc1 += aself * selfF.y;
    z += aself;
    const float zinv = 1.0f / z;
    float vv[VPL], lsum = 0.f;
    vv[0] = acc0;
    if (VPL == 2) vv[1] = acc1;
    #pragma unroll
    for (int k = 0; k < VPL; ++k) {
        const int ch = VPL * lane + k;
        vv[k] = fmaxf(vv[k] * zinv + b[ch], 0.f);
        lsum += vv[k];
    }
    const float mu = bf_sum(lsum) / D;
    float q = 0.f;
    #pragma unroll
    for (int k = 0; k < VPL; ++k) { vv[k] -= mu; q += vv[k] * vv[k]; }
    const float rstd = rsqrtf(bf_sum(q) / D + LN_EPS);
    #pragma unroll
    for (int k = 0; k < VPL; ++k) {
        const int ch = VPL * lane + k;
        vv[k] = gam[ch] * vv[k] * rstd + bet[ch];
    }
    if (POOL) {
        const int bg = batch[node];                 // uniform per wave
        atomicAdd(&sums[bg * D + lane], vv[0]);     // POOL only used with D=64
    } else {
        // fp16 intermediate (gemm2 would convert to fp16 anyway - same rounding)
        if (VPL == 2)
            *(__half2*)(outh + (size_t)node * D + 2 * lane) =
                __floats2half2_rn(vv[0], vv[1]);
        else
            outh[(size_t)node * D + lane] = __float2half_rn(vv[0]);
    }
}

// ================= fused GAT: TWO nodes per wave, interleaved chains (R2) ===========
template<int D, int POOL>
__global__ __launch_bounds__(256) void gat_aggr(
        const int* __restrict__ cnt, const unsigned short* __restrict__ ssrc,
        const float* __restrict__ S, const float* __restrict__ Dv,
        const __half* __restrict__ H,
        const float* __restrict__ b, const float* __restrict__ gam,
        const float* __restrict__ bet,
        __half* __restrict__ outh, const int* __restrict__ batch,
        float* __restrict__ sums) {
    constexpr int VPL = D / 64;
    const int lane = threadIdx.x & 63;
    const int wv   = threadIdx.x >> 6;
    const int nodeA = blockIdx.x * 8 + wv * 2;      // 2 nodes per wave
    const int nodeB = nodeA + 1;

    const int degA = min(__builtin_amdgcn_readfirstlane(cnt[nodeA]), CAP);
    const int degB = min(__builtin_amdgcn_readfirstlane(cnt[nodeB]), CAP);
    const float dscA = Dv[nodeA], dscB = Dv[nodeB];

    float tsA = S[nodeA] + dscA; tsA = tsA > 0.f ? tsA : 0.2f * tsA;
    float tsB = S[nodeB] + dscB; tsB = tsB > 0.f ? tsB : 0.2f * tsB;
    const float aselfA = __expf(tsA);
    const float aselfB = __expf(tsB);

    float2 selfFA, selfFB;
    if (VPL == 1) {
        selfFA = make_float2(__half2float(H[(size_t)nodeA * D + lane]), 0.f);
        selfFB = make_float2(__half2float(H[(size_t)nodeB * D + lane]), 0.f);
    } else {
        selfFA = __half22float2(*(const __half2*)(H + (size_t)nodeA * D + 2 * lane));
        selfFB = __half22float2(*(const __half2*)(H + (size_t)nodeB * D + 2 * lane));
    }

    float accA0 = 0.f, accA1 = 0.f, accB0 = 0.f, accB1 = 0.f;
    float zA, zB;

    if (degA <= 64 && degB <= 64) {
        int sA = 0, sB = 0;
        if (lane < degA) sA = ssrc[nodeA * CAP + lane];
        if (lane < degB) sB = ssrc[nodeB * CAP + lane];
        float tA = S[sA] + dscA;                    // idle lanes read S[0]: harmless
        float tB = S[sB] + dscB;
        tA = tA > 0.f ? tA : 0.2f * tA;
        tB = tB > 0.f ? tB : 0.2f * tB;
        const float aA = (lane < degA) ? __expf(tA) : 0.f;
        const float aB = (lane < degB) ? __expf(tB) : 0.f;
        zA = bf_sum(aA);
        zB = bf_sum(aB);
        const int abA = __float_as_int(aA), abB = __float_as_int(aB);

        const int nmA = (degA + 7) & ~7;
        const int nmB = (degB + 7) & ~7;
        const int nmax = max(nmA, nmB);
        for (int j = 0; j < nmax; j += 8) {
            const bool doA = j < nmA, doB = j < nmB;   // wave-uniform
            float afA[8], afB[8];
            __half2 hvA[8], hvB[8];
            __half hsA[8], hsB[8];
            if (doA) {
                #pragma unroll
                for (int u = 0; u < 8; ++u) {
                    const int sj = __builtin_amdgcn_readlane(sA, j + u);
                    afA[u] = __int_as_float(__builtin_amdgcn_readlane(abA, j + u));
                    const __half* hp = H + (size_t)sj * D;
                    if (VPL == 1) hsA[u] = hp[lane];
                    else          hvA[u] = *(const __half2*)(hp + 2 * lane);
                }
            }
            if (doB) {
                #pragma unroll
                for (int u = 0; u < 8; ++u) {
                    const int sj = __builtin_amdgcn_readlane(sB, j + u);
                    afB[u] = __int_as_float(__builtin_amdgcn_readlane(abB, j + u));
                    const __half* hp = H + (size_t)sj * D;
                    if (VPL == 1) hsB[u] = hp[lane];
                    else          hvB[u] = *(const __half2*)(hp + 2 * lane);
                }
            }
            if (doA) {
                #pragma unroll
                for (int u = 0; u < 8; ++u) {
                    if (VPL == 1) {
                        accA0 += afA[u] * __half2float(hsA[u]);
                    } else {
                        accA0 += afA[u] * __half2float(__low2half(hvA[u]));
                        accA1 += afA[u] * __half2float(__high2half(hvA[u]));
                    }
                }
            }
            if (doB) {
                #pragma unroll
                for (int u = 0; u < 8; ++u) {
                    if (VPL == 1) {
                        accB0 += afB[u] * __half2float(hsB[u]);
                    } else {
                        accB0 += afB[u] * __half2float(__low2half(hvB[u]));
                        accB1 += afB[u] * __half2float(__high2half(hvB[u]));
                    }
                }
            }
        }
    } else {
        aggr_one_generic<D>(nodeA, degA, lane, ssrc, S, dscA, H, accA0, accA1, zA);
        aggr_one_generic<D>(nodeB, degB, lane, ssrc, S, dscB, H, accB0, accB1, zB);
    }

    finish_node<D, POOL>(nodeA, lane, accA0, accA1, zA, aselfA, selfFA,
                         b, gam, bet, outh, batch, sums);
    finish_node<D, POOL>(nodeB, lane, accB0, accB1, zB, aselfB, selfFB,
                         b, gam, bet, outh, batch, sums);
}

// ================= head: mean (cnt via binary search on sorted batch) + 2 linears ====
__global__ void final_head(const float* __restrict__ sums, const int* __restrict__ batch,
                           const float* __restrict__ Wl, const float* __restrict__ bl,
                           const float* __restrict__ Wc, const float* __restrict__ bc,
                           float* __restrict__ out) {
    __shared__ float p[64];
    __shared__ float red[64];
    const int g = blockIdx.x, tid = threadIdx.x;
    int lo = 0, hi = NNODES;
    while (lo < hi) { int mid = (lo + hi) >> 1; if (batch[mid] < g) lo = mid + 1; else hi = mid; }
    int lo2 = lo, hi2 = NNODES;
    while (lo2 < hi2) { int mid = (lo2 + hi2) >> 1; if (batch[mid] < g + 1) lo2 = mid + 1; else hi2 = mid; }
    const float cnt = (float)(lo2 - lo);
    p[tid] = sums[g * 64 + tid] / fmaxf(cnt, 1.0f);
    __syncthreads();
    float t = bl[tid];
    #pragma unroll 8
    for (int k = 0; k < 64; ++k) t += Wl[tid * 64 + k] * p[k];
    red[tid] = Wc[tid] * t;
    __syncthreads();
    for (int s = 32; s > 0; s >>= 1) {
        if (tid < s) red[tid] += red[tid + s];
        __syncthreads();
    }
    if (tid == 0) out[g] = red[0] + bc[0];
}

extern "C" void kernel_launch(void* const* d_in, const int* in_sizes, int n_in,
                              void* d_out, int out_size, void* d_ws, size_t ws_size,
                              hipStream_t stream) {
    const int N = NNODES, E = NEDGES, G = NGRAPH;

    const float* x      = (const float*)d_in[0];
    const int*   ei     = (const int*)d_in[1];
    const int*   batch  = (const int*)d_in[2];
    const float* W1     = (const float*)d_in[3];
    const float* a1s    = (const float*)d_in[4];
    const float* a1d    = (const float*)d_in[5];
    const float* b1     = (const float*)d_in[6];
    const float* g1     = (const float*)d_in[7];
    const float* be1    = (const float*)d_in[8];
    const float* W2     = (const float*)d_in[9];
    const float* a2s    = (const float*)d_in[10];
    const float* a2d    = (const float*)d_in[11];
    const float* b2     = (const float*)d_in[12];
    const float* g2     = (const float*)d_in[13];
    const float* be2    = (const float*)d_in[14];
    const float* Wl     = (const float*)d_in[15];
    const float* bl     = (const float*)d_in[16];
    const float* Wc     = (const float*)d_in[17];
    const float* bc     = (const float*)d_in[18];

    // ---- workspace carve-up ----
    char* w = (char*)d_ws;
    __half* h1   = (__half*)w; w += (size_t)N * 128 * 2;   // fp16 H layer 1
    __half* v1h  = (__half*)w; w += (size_t)N * 128 * 2;   // fp16 LN'd layer-1 out
    __half* h2   = (__half*)w; w += (size_t)N * 64 * 2;    // fp16 H layer 2
    float* S1    = (float*)w; w += (size_t)N * 4;
    float* Dv1   = (float*)w; w += (size_t)N * 4;
    float* S2    = (float*)w; w += (size_t)N * 4;
    float* Dv2   = (float*)w; w += (size_t)N * 4;
    int* cnt     = (int*)w;   w += (size_t)N * 4;
    unsigned short* ssrc = (unsigned short*)w; w += (size_t)N * CAP * 2;
    _Float16* Bf1 = (_Float16*)w; w += (size_t)128 * 128 * 2;   // MFMA B-frags W1
    _Float16* Bf2 = (_Float16*)w; w += (size_t)64 * 128 * 2;    // MFMA B-frags W2
    float* sums  = (float*)w; w += (size_t)G * 64 * 4;

    const int TB = 256;

    // ---- zero cnt (capture-safe), then binning + W-frag prep in one kernel ----
    hipMemsetAsync(cnt, 0, (size_t)N * 4, stream);
    bin_prep<<<(E + TB - 1) / TB, TB, 0, stream>>>(ei, E, cnt, ssrc, W1, W2,
                                                   Bf1, Bf2, sums);

    // ---- layer 1 GEMM (128 -> 128), fp32 input staged via LDS ----
    gemm_scores_mfma<128, false><<<N / 64, 256, 0, stream>>>(x, Bf1, a1s, a1d,
                                                             h1, S1, Dv1);

    // ---- layer 1 aggregation + LN -> fp16 v1h ----
    gat_aggr<128, 0><<<N / 8, 256, 0, stream>>>(cnt, ssrc, S1, Dv1, h1, b1, g1, be1,
                                                v1h, nullptr, nullptr);

    // ---- layer 2 GEMM (128 -> 64), fp16 input staged via LDS ----
    gemm_scores_mfma<64, true><<<N / 64, 256, 0, stream>>>(v1h, Bf2, a2s, a2d,
                                                           h2, S2, Dv2);

    // ---- layer 2 aggregation + LN + pool ----
    gat_aggr<64, 1><<<N / 8, 256, 0, stream>>>(cnt, ssrc, S2, Dv2, h2, b2, g2, be2,
                                               nullptr, batch, sums);

    // ---- head ----
    final_head<<<G, 64, 0, stream>>>(sums, batch, Wl, bl, Wc, bc, (float*)d_out);
}

// Round 9
// 226.416 us; speedup vs baseline: 2.9440x; 1.0842x over previous
//
#include <hip/hip_runtime.h>
#include <hip/hip_fp16.h>
#include <math.h>

#define NNODES 40000
#define NEDGES 640000
#define NGRAPH 64
#define CAP 96                 // slots per dst bucket (max random-degree ~45)
constexpr float LN_EPS = 1e-5f;

// R1 LESSON (measured): multi-line divergent VMEM collapses throughput 4x.
//   SGPR-base + contiguous lane offset, ONE row per VMEM instruction, mandatory.
// R2 LESSON (measured): 2 nodes/wave interleaved = best aggr point.
// R3 LESSON (measured): 4 chains/wave REGRESSED (occupancy + imbalance).
// R4 LESSON (measured): fp16 MFMA GEMM works; 245.6us.
// R5 LESSON (measured): per-block W2 staging x5000 blocks = L2 thrash (+38MB HBM).
// R6 LESSON (measured): LDS-staged gemm A-tiles + fp16 intermediate -> 242us (BEST).
// R7 LESSON (measured): per-block __threadfence() on XCD-noncoherent L2 = L2
//   writeback x5000 -> 60->502us. NEVER fence/grid-sync per block.
// R8 LESSON (measured): R6 restore = 245.5us; aggr wall arithmetic confirmed
//   (~50cy per scattered wave-load per CU; 640k loads -> ~52us/layer floor).
// R9: dependency-split orchestration. prep_small (cnt zero + W-frags + sums zero,
//   replaces memset+half of bin_prep) -> merged gemm1+edge-binning (bin blocks
//   overlap atomics under MFMA; binning only needed by aggr1, not gemm1).
//   7 dispatches -> 6. Aggr/gemm bodies untouched.

typedef _Float16 v8h __attribute__((ext_vector_type(8)));
typedef float    v4f __attribute__((ext_vector_type(4)));

// ================= butterfly wave reduction (all lanes get result) =================
__device__ __forceinline__ float bf_sum(float v) {
    #pragma unroll
    for (int o = 32; o > 0; o >>= 1) v += __shfl_xor(v, o);
    return v;
}

// ====== prep_small: cnt zero + W1/W2 MFMA B-frag build + sums zero =================
// B-frag layout for v_mfma_f32_16x16x32_f16: lane l = g*16+lc holds B[k][n] with
// n = lc, k = ks*32 + g*8 + j (j=0..7). Same (g,j)->k map as the A frags below.
__global__ void prep_small(int* __restrict__ cnt,
                           const float* __restrict__ W1, const float* __restrict__ W2,
                           _Float16* __restrict__ Bf1, _Float16* __restrict__ Bf2,
                           float* __restrict__ sums) {
    const int t = blockIdx.x * 256 + threadIdx.x;
    if (t < NNODES) cnt[t] = 0;
    if (t < 128 * 128) {
        const int o = t >> 7, k = t & 127;             // W1[o][k]
        const int nt = o >> 4, lc = o & 15;
        const int ks = k >> 5, g = (k >> 3) & 3, j = k & 7;
        Bf1[(size_t)(((nt * 4 + ks) * 64 + g * 16 + lc) * 8 + j)] = (_Float16)W1[t];
    }
    if (t < 64 * 128) {
        const int o = t >> 7, k = t & 127;             // W2[o][k]
        const int nt = o >> 4, lc = o & 15;
        const int ks = k >> 5, g = (k >> 3) & 3, j = k & 7;
        Bf2[(size_t)(((nt * 4 + ks) * 64 + g * 16 + lc) * 8 + j)] = (_Float16)W2[t];
    }
    if (t < NGRAPH * 64) sums[t] = 0.f;
}

// ====== layer-1 GEMM (+scores) with edge-binning blocks appended ===================
// Blocks [0, NGB): MFMA gemm on a 64-node tile (identical body to R8's gemm).
// Blocks [NGB, NGB+NBB): bin 256 edges each (only consumed by aggr1, so safe to
// overlap with the gemm in the same dispatch).
template<int DOUT, bool F16IN, int NGB>
__global__ __launch_bounds__(256) void gemm_scores_bin(
        const void* __restrict__ Xin, const _Float16* __restrict__ Bfrag,
        const float* __restrict__ asrc, const float* __restrict__ adst,
        __half* __restrict__ H, float* __restrict__ S, float* __restrict__ Dv,
        const int* __restrict__ ei, int E,
        int* __restrict__ cnt, unsigned short* __restrict__ ssrc) {
    constexpr int NT = DOUT / 16;
    __shared__ _Float16 xs[64][136];
    const int tid = threadIdx.x;

    if (blockIdx.x >= NGB) {
        // ---------------- edge-binning block ----------------
        const int e = (blockIdx.x - NGB) * 256 + tid;
        if (e < E) {
            const int s = ei[e], d = ei[E + e];
            const int pos = atomicAdd(cnt + d, 1);
            if (pos < CAP) ssrc[d * CAP + pos] = (unsigned short)s;
        }
        return;
    }

    // ---------------- gemm block (R8 body) ----------------
    const int base = blockIdx.x * 64;

    if (F16IN) {
        const _Float16* Xh = (const _Float16*)Xin;
        for (int c = tid; c < 64 * 16; c += 256) {          // 16B chunks, coalesced
            const int row = c >> 4, c8 = c & 15;
            *(float4*)&xs[row][c8 * 8] =
                *(const float4*)(Xh + (size_t)(base + row) * 128 + c8 * 8);
        }
    } else {
        const float* Xf = (const float*)Xin;
        for (int c = tid; c < 64 * 32; c += 256) {          // float4 chunks, coalesced
            const int row = c >> 5, c4 = c & 31;
            const float4 v = *(const float4*)(Xf + (size_t)(base + row) * 128 + c4 * 4);
            _Float16 h4[4] = {(_Float16)v.x, (_Float16)v.y, (_Float16)v.z, (_Float16)v.w};
            *(uint2*)&xs[row][c4 * 4] = *(const uint2*)h4;
        }
    }
    __syncthreads();

    const int lane = tid & 63;
    const int wv   = tid >> 6;
    const int nb   = base + wv * 16;
    const int lc = lane & 15, g = lane >> 4;

    v8h a[4];
    #pragma unroll
    for (int ks = 0; ks < 4; ++ks)
        a[ks] = *(const v8h*)&xs[wv * 16 + lc][ks * 32 + g * 8];

    v4f acc[NT];
    #pragma unroll
    for (int nt = 0; nt < NT; ++nt) acc[nt] = (v4f){0.f, 0.f, 0.f, 0.f};

    #pragma unroll
    for (int ks = 0; ks < 4; ++ks) {
        #pragma unroll
        for (int nt = 0; nt < NT; ++nt) {
            const v8h bv = *(const v8h*)(Bfrag + (size_t)(((nt * 4 + ks) * 64 + lane) * 8));
            acc[nt] = __builtin_amdgcn_mfma_f32_16x16x32_f16(a[ks], bv, acc[nt], 0, 0, 0);
        }
    }

    float sp[4] = {0.f, 0.f, 0.f, 0.f}, dp[4] = {0.f, 0.f, 0.f, 0.f};
    #pragma unroll
    for (int nt = 0; nt < NT; ++nt) {
        const float as_ = asrc[nt * 16 + lc];
        const float ad_ = adst[nt * 16 + lc];
        #pragma unroll
        for (int r = 0; r < 4; ++r) {
            const float hv = acc[nt][r];
            H[(size_t)(nb + g * 4 + r) * DOUT + nt * 16 + lc] = __float2half_rn(hv);
            sp[r] += hv * as_;
            dp[r] += hv * ad_;
        }
    }
    #pragma unroll
    for (int o = 8; o > 0; o >>= 1) {
        #pragma unroll
        for (int r = 0; r < 4; ++r) {
            sp[r] += __shfl_xor(sp[r], o);
            dp[r] += __shfl_xor(dp[r], o);
        }
    }
    #pragma unroll
    for (int r = 0; r < 4; ++r) {
        if (lc == r) {
            S[nb + g * 4 + r]  = sp[r];
            Dv[nb + g * 4 + r] = dp[r];
        }
    }
}

// ================= layer-2 GEMM + scores (plain, R8 body) ==========================
template<int DOUT, bool F16IN>
__global__ __launch_bounds__(256) void gemm_scores_mfma(
        const void* __restrict__ Xin, const _Float16* __restrict__ Bfrag,
        const float* __restrict__ asrc, const float* __restrict__ adst,
        __half* __restrict__ H, float* __restrict__ S, float* __restrict__ Dv) {
    constexpr int NT = DOUT / 16;
    __shared__ _Float16 xs[64][136];
    const int tid = threadIdx.x;
    const int base = blockIdx.x * 64;

    if (F16IN) {
        const _Float16* Xh = (const _Float16*)Xin;
        for (int c = tid; c < 64 * 16; c += 256) {
            const int row = c >> 4, c8 = c & 15;
            *(float4*)&xs[row][c8 * 8] =
                *(const float4*)(Xh + (size_t)(base + row) * 128 + c8 * 8);
        }
    } else {
        const float* Xf = (const float*)Xin;
        for (int c = tid; c < 64 * 32; c += 256) {
            const int row = c >> 5, c4 = c & 31;
            const float4 v = *(const float4*)(Xf + (size_t)(base + row) * 128 + c4 * 4);
            _Float16 h4[4] = {(_Float16)v.x, (_Float16)v.y, (_Float16)v.z, (_Float16)v.w};
            *(uint2*)&xs[row][c4 * 4] = *(const uint2*)h4;
        }
    }
    __syncthreads();

    const int lane = tid & 63;
    const int wv   = tid >> 6;
    const int nb   = base + wv * 16;
    const int lc = lane & 15, g = lane >> 4;

    v8h a[4];
    #pragma unroll
    for (int ks = 0; ks < 4; ++ks)
        a[ks] = *(const v8h*)&xs[wv * 16 + lc][ks * 32 + g * 8];

    v4f acc[NT];
    #pragma unroll
    for (int nt = 0; nt < NT; ++nt) acc[nt] = (v4f){0.f, 0.f, 0.f, 0.f};

    #pragma unroll
    for (int ks = 0; ks < 4; ++ks) {
        #pragma unroll
        for (int nt = 0; nt < NT; ++nt) {
            const v8h bv = *(const v8h*)(Bfrag + (size_t)(((nt * 4 + ks) * 64 + lane) * 8));
            acc[nt] = __builtin_amdgcn_mfma_f32_16x16x32_f16(a[ks], bv, acc[nt], 0, 0, 0);
        }
    }

    float sp[4] = {0.f, 0.f, 0.f, 0.f}, dp[4] = {0.f, 0.f, 0.f, 0.f};
    #pragma unroll
    for (int nt = 0; nt < NT; ++nt) {
        const float as_ = asrc[nt * 16 + lc];
        const float ad_ = adst[nt * 16 + lc];
        #pragma unroll
        for (int r = 0; r < 4; ++r) {
            const float hv = acc[nt][r];
            H[(size_t)(nb + g * 4 + r) * DOUT + nt * 16 + lc] = __float2half_rn(hv);
            sp[r] += hv * as_;
            dp[r] += hv * ad_;
        }
    }
    #pragma unroll
    for (int o = 8; o > 0; o >>= 1) {
        #pragma unroll
        for (int r = 0; r < 4; ++r) {
            sp[r] += __shfl_xor(sp[r], o);
            dp[r] += __shfl_xor(dp[r], o);
        }
    }
    #pragma unroll
    for (int r = 0; r < 4; ++r) {
        if (lc == r) {
            S[nb + g * 4 + r]  = sp[r];
            Dv[nb + g * 4 + r] = dp[r];
        }
    }
}

// ================= generic single-node aggregation (rare big-deg path) ==============
template<int D>
__device__ __forceinline__ void aggr_one_generic(
        const int node, const int deg, const int lane,
        const unsigned short* __restrict__ ssrc, const float* __restrict__ S,
        const float dsc, const __half* __restrict__ H,
        float& acc0, float& acc1, float& z) {
    constexpr int VPL = D / 64;
    float zz = 0.f;
    const int r0 = node * CAP;
    for (int bse = 0; bse < deg; bse += 64) {
        const int n = min(64, deg - bse);
        int s = 0; float a = 0.f;
        if (lane < n) {
            s = ssrc[r0 + bse + lane];
            float t = S[s] + dsc;
            t = t > 0.f ? t : 0.2f * t;
            a = __expf(t);
        }
        zz += bf_sum(a);
        const int abits = __float_as_int(a);
        for (int j = 0; j < n; ++j) {
            const int sj = __builtin_amdgcn_readlane(s, j);
            const float aj = __int_as_float(__builtin_amdgcn_readlane(abits, j));
            const __half* hp = H + (size_t)sj * D;
            if (VPL == 1) {
                acc0 += aj * __half2float(hp[lane]);
            } else {
                const float2 f = __half22float2(*(const __half2*)(hp + 2 * lane));
                acc0 += aj * f.x; acc1 += aj * f.y;
            }
        }
    }
    z = zz;
}

// ===== epilogue: self-loop + normalize + bias + ReLU + LN + store (fp16 or pool) ====
template<int D, int POOL>
__device__ __forceinline__ void finish_node(
        const int node, const int lane,
        float acc0, float acc1, float z, const float aself, const float2 selfF,
        const float* __restrict__ b, const float* __restrict__ gam,
        const float* __restrict__ bet,
        __half* __restrict__ outh, const int* __restrict__ batch,
        float* __restrict__ sums) {
    constexpr int VPL = D / 64;
    acc0 += aself * selfF.x;
    if (VPL == 2) acc1 += aself * selfF.y;
    z += aself;
    const float zinv = 1.0f / z;
    float vv[VPL], lsum = 0.f;
    vv[0] = acc0;
    if (VPL == 2) vv[1] = acc1;
    #pragma unroll
    for (int k = 0; k < VPL; ++k) {
        const int ch = VPL * lane + k;
        vv[k] = fmaxf(vv[k] * zinv + b[ch], 0.f);
        lsum += vv[k];
    }
    const float mu = bf_sum(lsum) / D;
    float q = 0.f;
    #pragma unroll
    for (int k = 0; k < VPL; ++k) { vv[k] -= mu; q += vv[k] * vv[k]; }
    const float rstd = rsqrtf(bf_sum(q) / D + LN_EPS);
    #pragma unroll
    for (int k = 0; k < VPL; ++k) {
        const int ch = VPL * lane + k;
        vv[k] = gam[ch] * vv[k] * rstd + bet[ch];
    }
    if (POOL) {
        const int bg = batch[node];                 // uniform per wave
        atomicAdd(&sums[bg * D + lane], vv[0]);     // POOL only used with D=64
    } else {
        // fp16 intermediate (gemm2 would convert to fp16 anyway - same rounding)
        if (VPL == 2)
            *(__half2*)(outh + (size_t)node * D + 2 * lane) =
                __floats2half2_rn(vv[0], vv[1]);
        else
            outh[(size_t)node * D + lane] = __float2half_rn(vv[0]);
    }
}

// ================= fused GAT: TWO nodes per wave, interleaved chains (R2) ===========
template<int D, int POOL>
__global__ __launch_bounds__(256) void gat_aggr(
        const int* __restrict__ cnt, const unsigned short* __restrict__ ssrc,
        const float* __restrict__ S, const float* __restrict__ Dv,
        const __half* __restrict__ H,
        const float* __restrict__ b, const float* __restrict__ gam,
        const float* __restrict__ bet,
        __half* __restrict__ outh, const int* __restrict__ batch,
        float* __restrict__ sums) {
    constexpr int VPL = D / 64;
    const int lane = threadIdx.x & 63;
    const int wv   = threadIdx.x >> 6;
    const int nodeA = blockIdx.x * 8 + wv * 2;      // 2 nodes per wave
    const int nodeB = nodeA + 1;

    const int degA = min(__builtin_amdgcn_readfirstlane(cnt[nodeA]), CAP);
    const int degB = min(__builtin_amdgcn_readfirstlane(cnt[nodeB]), CAP);
    const float dscA = Dv[nodeA], dscB = Dv[nodeB];

    float tsA = S[nodeA] + dscA; tsA = tsA > 0.f ? tsA : 0.2f * tsA;
    float tsB = S[nodeB] + dscB; tsB = tsB > 0.f ? tsB : 0.2f * tsB;
    const float aselfA = __expf(tsA);
    const float aselfB = __expf(tsB);

    float2 selfFA, selfFB;
    if (VPL == 1) {
        selfFA = make_float2(__half2float(H[(size_t)nodeA * D + lane]), 0.f);
        selfFB = make_float2(__half2float(H[(size_t)nodeB * D + lane]), 0.f);
    } else {
        selfFA = __half22float2(*(const __half2*)(H + (size_t)nodeA * D + 2 * lane));
        selfFB = __half22float2(*(const __half2*)(H + (size_t)nodeB * D + 2 * lane));
    }

    float accA0 = 0.f, accA1 = 0.f, accB0 = 0.f, accB1 = 0.f;
    float zA, zB;

    if (degA <= 64 && degB <= 64) {
        int sA = 0, sB = 0;
        if (lane < degA) sA = ssrc[nodeA * CAP + lane];
        if (lane < degB) sB = ssrc[nodeB * CAP + lane];
        float tA = S[sA] + dscA;                    // idle lanes read S[0]: harmless
        float tB = S[sB] + dscB;
        tA = tA > 0.f ? tA : 0.2f * tA;
        tB = tB > 0.f ? tB : 0.2f * tB;
        const float aA = (lane < degA) ? __expf(tA) : 0.f;
        const float aB = (lane < degB) ? __expf(tB) : 0.f;
        zA = bf_sum(aA);
        zB = bf_sum(aB);
        const int abA = __float_as_int(aA), abB = __float_as_int(aB);

        const int nmA = (degA + 7) & ~7;
        const int nmB = (degB + 7) & ~7;
        const int nmax = max(nmA, nmB);
        for (int j = 0; j < nmax; j += 8) {
            const bool doA = j < nmA, doB = j < nmB;   // wave-uniform
            float afA[8], afB[8];
            __half2 hvA[8], hvB[8];
            __half hsA[8], hsB[8];
            if (doA) {
                #pragma unroll
                for (int u = 0; u < 8; ++u) {
                    const int sj = __builtin_amdgcn_readlane(sA, j + u);
                    afA[u] = __int_as_float(__builtin_amdgcn_readlane(abA, j + u));
                    const __half* hp = H + (size_t)sj * D;
                    if (VPL == 1) hsA[u] = hp[lane];
                    else          hvA[u] = *(const __half2*)(hp + 2 * lane);
                }
            }
            if (doB) {
                #pragma unroll
                for (int u = 0; u < 8; ++u) {
                    const int sj = __builtin_amdgcn_readlane(sB, j + u);
                    afB[u] = __int_as_float(__builtin_amdgcn_readlane(abB, j + u));
                    const __half* hp = H + (size_t)sj * D;
                    if (VPL == 1) hsB[u] = hp[lane];
                    else          hvB[u] = *(const __half2*)(hp + 2 * lane);
                }
            }
            if (doA) {
                #pragma unroll
                for (int u = 0; u < 8; ++u) {
                    if (VPL == 1) {
                        accA0 += afA[u] * __half2float(hsA[u]);
                    } else {
                        accA0 += afA[u] * __half2float(__low2half(hvA[u]));
                        accA1 += afA[u] * __half2float(__high2half(hvA[u]));
                    }
                }
            }
            if (doB) {
                #pragma unroll
                for (int u = 0; u < 8; ++u) {
                    if (VPL == 1) {
                        accB0 += afB[u] * __half2float(hsB[u]);
                    } else {
                        accB0 += afB[u] * __half2float(__low2half(hvB[u]));
                        accB1 += afB[u] * __half2float(__high2half(hvB[u]));
                    }
                }
            }
        }
    } else {
        aggr_one_generic<D>(nodeA, degA, lane, ssrc, S, dscA, H, accA0, accA1, zA);
        aggr_one_generic<D>(nodeB, degB, lane, ssrc, S, dscB, H, accB0, accB1, zB);
    }

    finish_node<D, POOL>(nodeA, lane, accA0, accA1, zA, aselfA, selfFA,
                         b, gam, bet, outh, batch, sums);
    finish_node<D, POOL>(nodeB, lane, accB0, accB1, zB, aselfB, selfFB,
                         b, gam, bet, outh, batch, sums);
}

// ================= head: mean (cnt via binary search on sorted batch) + 2 linears ====
__global__ void final_head(const float* __restrict__ sums, const int* __restrict__ batch,
                           const float* __restrict__ Wl, const float* __restrict__ bl,
                           const float* __restrict__ Wc, const float* __restrict__ bc,
                           float* __restrict__ out) {
    __shared__ float p[64];
    __shared__ float red[64];
    const int g = blockIdx.x, tid = threadIdx.x;
    int lo = 0, hi = NNODES;
    while (lo < hi) { int mid = (lo + hi) >> 1; if (batch[mid] < g) lo = mid + 1; else hi = mid; }
    int lo2 = lo, hi2 = NNODES;
    while (lo2 < hi2) { int mid = (lo2 + hi2) >> 1; if (batch[mid] < g + 1) lo2 = mid + 1; else hi2 = mid; }
    const float cnt = (float)(lo2 - lo);
    p[tid] = sums[g * 64 + tid] / fmaxf(cnt, 1.0f);
    __syncthreads();
    float t = bl[tid];
    #pragma unroll 8
    for (int k = 0; k < 64; ++k) t += Wl[tid * 64 + k] * p[k];
    red[tid] = Wc[tid] * t;
    __syncthreads();
    for (int s = 32; s > 0; s >>= 1) {
        if (tid < s) red[tid] += red[tid + s];
        __syncthreads();
    }
    if (tid == 0) out[g] = red[0] + bc[0];
}

extern "C" void kernel_launch(void* const* d_in, const int* in_sizes, int n_in,
                              void* d_out, int out_size, void* d_ws, size_t ws_size,
                              hipStream_t stream) {
    const int N = NNODES, E = NEDGES, G = NGRAPH;

    const float* x      = (const float*)d_in[0];
    const int*   ei     = (const int*)d_in[1];
    const int*   batch  = (const int*)d_in[2];
    const float* W1     = (const float*)d_in[3];
    const float* a1s    = (const float*)d_in[4];
    const float* a1d    = (const float*)d_in[5];
    const float* b1     = (const float*)d_in[6];
    const float* g1     = (const float*)d_in[7];
    const float* be1    = (const float*)d_in[8];
    const float* W2     = (const float*)d_in[9];
    const float* a2s    = (const float*)d_in[10];
    const float* a2d    = (const float*)d_in[11];
    const float* b2     = (const float*)d_in[12];
    const float* g2     = (const float*)d_in[13];
    const float* be2    = (const float*)d_in[14];
    const float* Wl     = (const float*)d_in[15];
    const float* bl     = (const float*)d_in[16];
    const float* Wc     = (const float*)d_in[17];
    const float* bc     = (const float*)d_in[18];

    // ---- workspace carve-up ----
    char* w = (char*)d_ws;
    __half* h1   = (__half*)w; w += (size_t)N * 128 * 2;   // fp16 H layer 1
    __half* v1h  = (__half*)w; w += (size_t)N * 128 * 2;   // fp16 LN'd layer-1 out
    __half* h2   = (__half*)w; w += (size_t)N * 64 * 2;    // fp16 H layer 2
    float* S1    = (float*)w; w += (size_t)N * 4;
    float* Dv1   = (float*)w; w += (size_t)N * 4;
    float* S2    = (float*)w; w += (size_t)N * 4;
    float* Dv2   = (float*)w; w += (size_t)N * 4;
    int* cnt     = (int*)w;   w += (size_t)N * 4;
    unsigned short* ssrc = (unsigned short*)w; w += (size_t)N * CAP * 2;
    _Float16* Bf1 = (_Float16*)w; w += (size_t)128 * 128 * 2;   // MFMA B-frags W1
    _Float16* Bf2 = (_Float16*)w; w += (size_t)64 * 128 * 2;    // MFMA B-frags W2
    float* sums  = (float*)w; w += (size_t)G * 64 * 4;

    // ---- prep: cnt zero + W-frag build + sums zero (one small dispatch) ----
    prep_small<<<(N + 255) / 256, 256, 0, stream>>>(cnt, W1, W2, Bf1, Bf2, sums);

    // ---- layer 1 GEMM (128 -> 128) with edge-binning blocks overlapped ----
    constexpr int NGB1 = NNODES / 64;                       // 625 gemm blocks
    const int NBB = (E + 255) / 256;                        // 2500 bin blocks
    gemm_scores_bin<128, false, NGB1><<<NGB1 + NBB, 256, 0, stream>>>(
        x, Bf1, a1s, a1d, h1, S1, Dv1, ei, E, cnt, ssrc);

    // ---- layer 1 aggregation + LN -> fp16 v1h ----
    gat_aggr<128, 0><<<N / 8, 256, 0, stream>>>(cnt, ssrc, S1, Dv1, h1, b1, g1, be1,
                                                v1h, nullptr, nullptr);

    // ---- layer 2 GEMM (128 -> 64), fp16 input staged via LDS ----
    gemm_scores_mfma<64, true><<<N / 64, 256, 0, stream>>>(v1h, Bf2, a2s, a2d,
                                                           h2, S2, Dv2);

    // ---- layer 2 aggregation + LN + pool ----
    gat_aggr<64, 1><<<N / 8, 256, 0, stream>>>(cnt, ssrc, S2, Dv2, h2, b2, g2, be2,
                                               nullptr, batch, sums);

    // ---- head ----
    final_head<<<G, 64, 0, stream>>>(sums, batch, Wl, bl, Wc, bc, (float*)d_out);
}